// Round 9
// baseline (335.905 us; speedup 1.0000x reference)
//
#include <hip/hip_runtime.h>
#include <hip/hip_fp16.h>

// GCN 2-layer GraphConv (norm='both'), fp32 in/out, fp16 intermediates.
// Round 9: lean pulls — pre-scaled h1 (no per-edge hist_s/rsqrt), pull32 at
//          4 lanes/edge x uint4, wave-uniform early break in round loops,
//          32-bit gather offsets. K1/K2 atomic shadows unchanged.
//
// ws: int hist_s[N] | hist_d[N](=deg) | rowptr[N] | bsum[1024] | col[E] | rank[E]
//     float in_norm[N]
//     half h1[64N] | h2[32N]

#define SCAN_BLK 1024

// ---- K1: hist_d + rank (interleaved blocks) || h1 = x @ W1 unscaled ----
__global__ __launch_bounds__(256) void k1_histd_xw1(
    const int* __restrict__ dst, int* __restrict__ hist_d, int* __restrict__ rank,
    const float* __restrict__ x, const float* __restrict__ W,
    __half* __restrict__ h1, int E, int n, int GH, int GX) {
  __shared__ float Ws[64 * 64];
  __shared__ float xs[16 * 64];
  int bid = blockIdx.x;
  int Mn = (GH < GX) ? GH : GX;
  bool isHist;
  int idx;
  if (bid < 2 * Mn) { isHist = !(bid & 1); idx = bid >> 1; }
  else               { isHist = (GH > GX); idx = bid - 2 * Mn + Mn; }

  if (isHist) {
    int e = idx * 256 + threadIdx.x;
    if (e < E) rank[e] = atomicAdd(&hist_d[dst[e]], 1);
    return;
  }
  int t = threadIdx.x;
#pragma unroll
  for (int i = 0; i < 16; i++) Ws[i * 256 + t] = W[i * 256 + t];
  int row0 = idx * 16;
#pragma unroll
  for (int i = 0; i < 4; i++) {
    int gi = i * 256 + t;
    int r = gi >> 6, k = gi & 63;
    int row = row0 + r;
    xs[gi] = (row < n) ? x[row * 64 + k] : 0.0f;
  }
  __syncthreads();
  int c = t & 63, rq = t >> 6;
  float acc[4] = {0.f, 0.f, 0.f, 0.f};
#pragma unroll 16
  for (int k = 0; k < 64; k++) {
    float w = Ws[k * 64 + c];
#pragma unroll
    for (int rr = 0; rr < 4; rr++) acc[rr] += xs[(rq + rr * 4) * 64 + k] * w;
  }
#pragma unroll
  for (int rr = 0; rr < 4; rr++) {
    int row = row0 + rq + rr * 4;
    if (row < n) h1[(size_t)row * 64 + c] = __float2half(acc[rr]);
  }
}

// ---- scan of hist_d -> rowptr, fused in_norm ----
__global__ __launch_bounds__(256) void scan_local(const int* __restrict__ hist_d,
                                                  int* __restrict__ rowptr,
                                                  int* __restrict__ bsum,
                                                  float* __restrict__ in_norm, int n) {
  __shared__ int tmp[256];
  int t = threadIdx.x;
  int base = blockIdx.x * SCAN_BLK + t * 4;
  int v[4], s = 0;
#pragma unroll
  for (int i = 0; i < 4; i++) {
    v[i] = (base + i < n) ? hist_d[base + i] : 0;
    s += v[i];
  }
#pragma unroll
  for (int i = 0; i < 4; i++)
    if (base + i < n) in_norm[base + i] = rsqrtf(fmaxf((float)v[i], 1.0f));
  tmp[t] = s;
  __syncthreads();
#pragma unroll
  for (int off = 1; off < 256; off <<= 1) {
    int val = (t >= off) ? tmp[t - off] : 0;
    __syncthreads();
    tmp[t] += val;
    __syncthreads();
  }
  int run = tmp[t] - s;
#pragma unroll
  for (int i = 0; i < 4; i++) {
    if (base + i < n) rowptr[base + i] = run;
    run += v[i];
  }
  if (t == 255) bsum[blockIdx.x] = tmp[255];
}

__global__ __launch_bounds__(128) void scan_bsums(int* __restrict__ bsum, int nb) {
  __shared__ int tmp[128];
  int t = threadIdx.x;
  int v = (t < nb) ? bsum[t] : 0;
  tmp[t] = v;
  __syncthreads();
#pragma unroll
  for (int off = 1; off < 128; off <<= 1) {
    int val = (t >= off) ? tmp[t - off] : 0;
    __syncthreads();
    tmp[t] += val;
    __syncthreads();
  }
  if (t < nb) bsum[t] = tmp[t] - v;
}

__global__ __launch_bounds__(256) void scan_add(int* __restrict__ out,
                                                const int* __restrict__ bsum, int n) {
  int i = blockIdx.x * 256 + threadIdx.x;
  if (i < n) out[i] += bsum[i / SCAN_BLK];
}

// ---- K2: hist_s atomics || CSR placement (place hides in atomic shadow) ----
__global__ __launch_bounds__(256) void k2_hists_place(
    const int* __restrict__ src, const int* __restrict__ dst,
    const int* __restrict__ rowptr, const int* __restrict__ rank,
    int* __restrict__ hist_s, int* __restrict__ col, int E) {
  int e = blockIdx.x * 256 + threadIdx.x;
  if (e < E) {
    int s = src[e];
    atomicAdd(&hist_s[s], 1);
    col[rowptr[dst[e]] + rank[e]] = s;
  }
}

// ---- scale h1 rows by out_norm = rsqrt(hist_s): removes per-edge scale ----
// thread = one uint4 (8 halves); 8 threads/row.
__global__ __launch_bounds__(256) void scale_h1(__half* __restrict__ h1,
                                                const int* __restrict__ hist_s, int n) {
  int gid = blockIdx.x * 256 + threadIdx.x;
  int row = gid >> 3;
  if (row >= n) return;
  float nn = rsqrtf(fmaxf((float)hist_s[row], 1.0f));
  uint4* p = (uint4*)h1 + gid;
  uint4 v = *p;
  __half2* hp = reinterpret_cast<__half2*>(&v);
#pragma unroll
  for (int i = 0; i < 4; i++) {
    float2 f = __half22float2(hp[i]);
    f.x *= nn;
    f.y *= nn;
    hp[i] = __float22half2_rn(f);
  }
  *p = v;
}

__device__ inline void acc8h_add(float* a, uint4 r) {
  const __half2* hp = reinterpret_cast<const __half2*>(&r);
#pragma unroll
  for (int i = 0; i < 4; i++) {
    float2 f = __half22float2(hp[i]);
    a[2 * i] += f.x;
    a[2 * i + 1] += f.y;
  }
}

// ---- pull64 + fused xw2 (h1 pre-scaled; pure adds) ----
// wave w = node; sub = l>>3 (8 edge slots), fq = l&7 (16B of 128B row).
__global__ __launch_bounds__(256) void pull64_xw2(
    const int* __restrict__ rowptr, const int* __restrict__ deg,
    const int* __restrict__ col, const __half* __restrict__ h1,
    const int* __restrict__ hist_s, const float* __restrict__ in_norm,
    const float* __restrict__ b1, const float* __restrict__ W2,
    __half* __restrict__ h2, int n) {
  __shared__ float W2s[64 * 32];
  __shared__ float xrow[4][64];
  int t = threadIdx.x;
#pragma unroll
  for (int i = 0; i < 8; i++) W2s[i * 256 + t] = W2[i * 256 + t];

  int w = t >> 6;
  int node = blockIdx.x * 4 + w;
  int l = t & 63;
  int sub = l >> 3, fq = l & 7;

  if (node < n) {
    int beg = rowptr[node];
    int end = beg + deg[node];
    float acc[8] = {0, 0, 0, 0, 0, 0, 0, 0};
    for (int base = beg; base < end; base += 64) {
      int cj = base + l;
      int colv = (cj < end) ? col[cj] : 0;  // one coalesced 64-index load
#pragma unroll
      for (int r = 0; r < 8; r++) {
        if (base + r * 8 >= end) break;     // wave-uniform -> s_cbranch
        int s = __shfl(colv, r * 8 + sub);  // wave-uniform shfl (EXEC-safe)
        int jj = base + r * 8 + sub;
        if (jj < end) {
          unsigned off = ((unsigned)s << 7) | ((unsigned)fq << 4);
          uint4 rv = *(const uint4*)((const char*)h1 + off);
          acc8h_add(acc, rv);
        }
      }
    }
#pragma unroll
    for (int d = 8; d <= 32; d <<= 1) {
#pragma unroll
      for (int i = 0; i < 8; i++) acc[i] += __shfl_xor(acc[i], d);
    }
    if (sub == 0) {
      float innv = in_norm[node];
      float onnv = rsqrtf(fmaxf((float)hist_s[node], 1.0f));
      float4 ba = ((const float4*)b1)[fq * 2];
      float4 bb = ((const float4*)b1)[fq * 2 + 1];
      float bv[8] = {ba.x, ba.y, ba.z, ba.w, bb.x, bb.y, bb.z, bb.w};
#pragma unroll
      for (int i = 0; i < 8; i++)
        xrow[w][fq * 8 + i] = fmaxf(acc[i] * innv + bv[i], 0.0f) * onnv;
    }
  }
  __syncthreads();
  // phase 2: h2[node,32] = xrow @ W2  (threads 0..127)
  if (t < 128) {
    int w2 = t >> 5, c = t & 31;
    int nd = blockIdx.x * 4 + w2;
    if (nd < n) {
      float dot = 0.f;
#pragma unroll 16
      for (int k = 0; k < 64; k++) dot += xrow[w2][k] * W2s[k * 32 + c];
      h2[(size_t)nd * 32 + c] = __float2half(dot);
    }
  }
}

// ---- pull 32 feats + epilogue: 16 edge slots x 4 lanes x uint4 (16B) ----
// slot = l>>2 (0..15), fq4 = l&3 (16B of 64B row); 8 float accs/lane.
__global__ __launch_bounds__(256) void gcn_pull32(const int* __restrict__ rowptr,
                                                  const int* __restrict__ deg,
                                                  const int* __restrict__ col,
                                                  const __half* __restrict__ h,
                                                  const float* __restrict__ in_norm,
                                                  const float* __restrict__ b2,
                                                  float* __restrict__ out, int n) {
  int t = threadIdx.x;
  int node = blockIdx.x * 4 + (t >> 6);
  if (node >= n) return;
  int l = t & 63;
  int slot = l >> 2, fq4 = l & 3;
  int beg = rowptr[node];
  int end = beg + deg[node];
  float acc[8] = {0, 0, 0, 0, 0, 0, 0, 0};
  for (int base = beg; base < end; base += 64) {
    int cj = base + l;
    int colv = (cj < end) ? col[cj] : 0;
#pragma unroll
    for (int r = 0; r < 4; r++) {
      if (base + r * 16 >= end) break;       // wave-uniform
      int s = __shfl(colv, r * 16 + slot);   // wave-uniform shfl
      int jj = base + r * 16 + slot;
      if (jj < end) {
        unsigned off = ((unsigned)s << 6) | ((unsigned)fq4 << 4);
        uint4 rv = *(const uint4*)((const char*)h + off);
        acc8h_add(acc, rv);
      }
    }
  }
#pragma unroll
  for (int d = 4; d <= 32; d <<= 1) {
#pragma unroll
    for (int i = 0; i < 8; i++) acc[i] += __shfl_xor(acc[i], d);
  }
  if (slot == 0) {  // lanes fq4 = 0..3, each owns 8 consecutive feats
    float s = in_norm[node];
    float4 b0 = ((const float4*)b2)[fq4 * 2];
    float4 b1v = ((const float4*)b2)[fq4 * 2 + 1];
    float4 o0, o1;
    o0.x = acc[0] * s + b0.x;
    o0.y = acc[1] * s + b0.y;
    o0.z = acc[2] * s + b0.z;
    o0.w = acc[3] * s + b0.w;
    o1.x = acc[4] * s + b1v.x;
    o1.y = acc[5] * s + b1v.y;
    o1.z = acc[6] * s + b1v.z;
    o1.w = acc[7] * s + b1v.w;
    ((float4*)out)[(size_t)node * 8 + fq4 * 2] = o0;
    ((float4*)out)[(size_t)node * 8 + fq4 * 2 + 1] = o1;
  }
}

extern "C" void kernel_launch(void* const* d_in, const int* in_sizes, int n_in,
                              void* d_out, int out_size, void* d_ws, size_t ws_size,
                              hipStream_t stream) {
  const float* x   = (const float*)d_in[0];
  const int*   src = (const int*)d_in[1];
  const int*   dst = (const int*)d_in[2];
  const float* W1  = (const float*)d_in[3];
  const float* b1  = (const float*)d_in[4];
  const float* W2  = (const float*)d_in[5];
  const float* b2  = (const float*)d_in[6];
  float* out = (float*)d_out;

  const int N = in_sizes[0] / 64;   // 100000
  const int E = in_sizes[1];        // 1600000
  const int NB = (N + SCAN_BLK - 1) / SCAN_BLK;

  int* hist_s = (int*)d_ws;                    // N
  int* hist_d = hist_s + N;                    // N (doubles as deg)
  int* rowptr = hist_d + N;                    // N
  int* bsum   = rowptr + N;                    // 1024
  int* col    = bsum + 1024;                   // E
  int* rank   = col + E;                       // E
  float* in_norm = (float*)(rank + E);         // N
  __half* h1  = (__half*)(in_norm + N);        // 64N halves
  __half* h2  = h1 + (size_t)64 * N;           // 32N halves

  hipMemsetAsync(hist_s, 0, (size_t)2 * N * sizeof(int), stream);

  int GH = (E + 255) / 256;
  int GX = (N + 15) / 16;
  k1_histd_xw1<<<GH + GX, 256, 0, stream>>>(dst, hist_d, rank, x, W1, h1, E, N, GH, GX);
  scan_local<<<NB, 256, 0, stream>>>(hist_d, rowptr, bsum, in_norm, N);
  scan_bsums<<<1, 128, 0, stream>>>(bsum, NB);
  scan_add<<<(N + 255) / 256, 256, 0, stream>>>(rowptr, bsum, N);
  k2_hists_place<<<GH, 256, 0, stream>>>(src, dst, rowptr, rank, hist_s, col, E);
  scale_h1<<<(N * 8 + 255) / 256, 256, 0, stream>>>(h1, hist_s, N);
  pull64_xw2<<<(N + 3) / 4, 256, 0, stream>>>(rowptr, hist_d, col, h1, hist_s,
                                              in_norm, b1, W2, h2, N);
  gcn_pull32<<<(N + 3) / 4, 256, 0, stream>>>(rowptr, hist_d, col, h2, in_norm, b2, out, N);
}